// Round 7
// baseline (236.779 us; speedup 1.0000x reference)
//
#include <hip/hip_runtime.h>
#include <stdint.h>
#include <math.h>

#define NPTS 16384
#define DEV 62
#define NEVENT 2048
#define NSAMPLE 64
#define CH 64
#define NBATCH 4
#define STOT (NBATCH * NEVENT)               // 8192 queries
#define M_PER_BATCH (NEVENT * NSAMPLE * CH)  // 8,388,608 elements per batch

// ws layout (d_ws is ~400 MB, proven safe: R4 reproduced R3's failure without
// ws, so the R3 failure was the FMA-selection bug, not ws corruption):
//   idx_ws   int  [STOT*64]   2 MB
//   mean_ws  f32  [STOT*64]   2 MB
//   partial  f32  [STOT]      32 KB   (contiguous -> coalesced reduce)
//   inv_std  f32  [NBATCH]
#define OUT1_BASE 16384

// ---------------------------------------------------------------------------
// Pass 1 (fused knn + stats). One block (256 thr) per query.
// Phase A (wave 0 only): ball-query scan of xy in 64-point chunks with
// ballot-compaction into LDS (ascending index order == jnp.sort + first 64),
// early exit once 64 found (~33 of 256 chunks at ~3.1% density).
// DISTANCE CHAIN IS FROZEN (bit-exact vs harness np ref, verified R6):
//   norms: round(x*x), round(y*y), one add   (no FMA)
//   dot  : fma(qy,py, round(qx*px))          (XLA k=2 contraction)
//   final: sub(add(ssq,ssp), mul(2,dot)); exclude when d > 0.01f
// Phase B (all 4 waves): gather rows, per-channel mean, centered^2 partial.
// c2 = channel pair (0..31), kq = sample group (0..7); lanes 0..30 read
// contiguous float2 slices of the 248 B event row; lane 31 reads xy.
// ---------------------------------------------------------------------------
__global__ __launch_bounds__(256) void knn_stats_kernel(
    const float2* __restrict__ xy,            // f32 (B,N,2)
    const float* __restrict__ ev,             // f32 (B,N,62)
    const int* __restrict__ fps,              // (B,NEVENT)
    float* __restrict__ out,                  // new_xy at [0..16383]
    int* __restrict__ idx_ws,
    float* __restrict__ mean_ws,
    float* __restrict__ partial)
{
    int s = blockIdx.x;
    int b = s >> 11;
    int tid = threadIdx.x;

    __shared__ int sidx[NSAMPLE];
    __shared__ float ssum[2][256];
    __shared__ float smean[CH];
    __shared__ float swred[4];

    const float2* xyb = xy + b * NPTS;

    if (tid < 64) {                           // wave 0: the scan
        int lane = tid;
        int qi = fps[s];
        float2 q = xyb[qi];
        if (lane == 0) ((float2*)out)[s] = q; // exact f32 passthrough

        float ssq = __fadd_rn(__fmul_rn(q.x, q.x), __fmul_rn(q.y, q.y));
        const float thr = 0.01f;

        int m = 0;
        int first = -1;
        for (int base = 0; base < NPTS; base += 64) {
            float2 p = xyb[base + lane];
            float ssp = __fadd_rn(__fmul_rn(p.x, p.x), __fmul_rn(p.y, p.y));
            float dot = __builtin_fmaf(q.y, p.y, __fmul_rn(q.x, p.x));
            float d   = __fsub_rn(__fadd_rn(ssq, ssp), __fmul_rn(2.0f, dot));
            bool ok = !(d > thr);
            unsigned long long bal = __ballot(ok);
            if (first < 0 && bal != 0ull)
                first = (int)(base + (__ffsll((unsigned long long)bal) - 1));
            if (ok) {
                int pos = m + __popcll(bal & ((1ull << lane) - 1ull));
                if (pos < NSAMPLE) sidx[pos] = base + lane;
            }
            m += __popcll(bal);
            if (m >= NSAMPLE) break;          // wave-uniform
        }
        if (m < NSAMPLE) {
            for (int p = m + lane; p < NSAMPLE; p += 64)
                sidx[p] = first;
        }
    }
    __syncthreads();

    if (tid < NSAMPLE) idx_ws[s * NSAMPLE + tid] = sidx[tid];

    int c2 = tid & 31;
    int kq = tid >> 5;
    const float* evb = ev + (size_t)b * NPTS * DEV;

    float g0[8], g1[8];
    float a0 = 0.f, a1 = 0.f;
#pragma unroll
    for (int j = 0; j < 8; ++j) {
        int row = sidx[8 * j + kq];
        float2 v;
        if (c2 < 31) v = *(const float2*)(evb + (size_t)row * DEV + 2 * c2);
        else         v = xyb[row];
        g0[j] = v.x; g1[j] = v.y;
        a0 += v.x;   a1 += v.y;
    }
    ssum[0][tid] = a0;
    ssum[1][tid] = a1;
    __syncthreads();

    if (tid < CH) {
        int which = tid >> 5, cc = tid & 31;
        float t = 0.f;
#pragma unroll
        for (int q = 0; q < 8; ++q) t += ssum[which][q * 32 + cc];
        smean[2 * cc + which] = t * (1.0f / NSAMPLE);
    }
    __syncthreads();

    if (tid < CH) mean_ws[s * CH + tid] = smean[tid];

    float m0 = smean[2 * c2], m1 = smean[2 * c2 + 1];
    float ss = 0.f;
#pragma unroll
    for (int j = 0; j < 8; ++j) {
        float c0 = g0[j] - m0;
        float c1 = g1[j] - m1;
        ss += c0 * c0 + c1 * c1;
    }

    for (int off = 32; off > 0; off >>= 1) ss += __shfl_down(ss, off, 64);
    if ((tid & 63) == 0) swred[tid >> 6] = ss;
    __syncthreads();
    if (tid == 0) partial[s] = swred[0] + swred[1] + swred[2] + swred[3];
}

// ---------------------------------------------------------------------------
// Pass 2: per-batch std (ddof=1), f64 accumulation over contiguous partials.
// ---------------------------------------------------------------------------
__global__ __launch_bounds__(256) void reduce_std_kernel(
    const float* __restrict__ partial, float* __restrict__ inv_std)
{
    int b = blockIdx.x;
    int tid = threadIdx.x;
    double acc = 0.0;
    for (int i = tid; i < NEVENT; i += 256)
        acc += (double)partial[b * NEVENT + i];
    __shared__ double sd[256];
    sd[tid] = acc;
    __syncthreads();
    for (int off = 128; off > 0; off >>= 1) {
        if (tid < off) sd[tid] += sd[tid + off];
        __syncthreads();
    }
    if (tid == 0) {
        double stdv = sqrt(sd[0] / (double)(M_PER_BATCH - 1));
        inv_std[b] = (float)(1.0 / (stdv + 1e-5));
    }
}

// ---------------------------------------------------------------------------
// Pass 3: finalize. Load idx/mean from ws into LDS, re-gather (events are
// L2/L3-resident), normalize + affine, write the 16 KB output region once.
// float2 slot for (k = 8j+kq, pair c2) = 256*j + tid: fully coalesced.
// ---------------------------------------------------------------------------
__global__ __launch_bounds__(256) void finalize_kernel(
    const float2* __restrict__ xy,
    const float* __restrict__ ev,
    const int* __restrict__ idx_ws,
    const float* __restrict__ mean_ws,
    const float* __restrict__ inv_std,
    const float* __restrict__ alpha,          // f32 [64]
    const float* __restrict__ beta,           // f32 [64]
    float* __restrict__ out)
{
    int s = blockIdx.x;
    int b = s >> 11;
    int tid = threadIdx.x;

    __shared__ int sidx[NSAMPLE];
    __shared__ float sm[CH], sa[CH], sbet[CH];

    if (tid < NSAMPLE) {
        sidx[tid] = idx_ws[s * NSAMPLE + tid];
        sm[tid] = mean_ws[s * CH + tid];
    } else if (tid < 128) {
        sa[tid - 64] = alpha[tid - 64];
        sbet[tid - 64] = beta[tid - 64];
    }
    __syncthreads();

    int c2 = tid & 31;
    int kq = tid >> 5;
    float inv = inv_std[b];

    const float* evb = ev + (size_t)b * NPTS * DEV;
    const float2* xyb = xy + b * NPTS;

    float m0 = sm[2 * c2],    m1 = sm[2 * c2 + 1];
    float al0 = sa[2 * c2],   al1 = sa[2 * c2 + 1];
    float be0 = sbet[2 * c2], be1 = sbet[2 * c2 + 1];

    float2* outp = (float2*)(out + OUT1_BASE + (size_t)s * (NSAMPLE * CH));
#pragma unroll
    for (int j = 0; j < 8; ++j) {
        int row = sidx[8 * j + kq];
        float2 v;
        if (c2 < 31) v = *(const float2*)(evb + (size_t)row * DEV + 2 * c2);
        else         v = xyb[row];
        float2 r;
        r.x = al0 * ((v.x - m0) * inv) + be0;
        r.y = al1 * ((v.y - m1) * inv) + be1;
        outp[256 * j + tid] = r;
    }
}

extern "C" void kernel_launch(void* const* d_in, const int* in_sizes, int n_in,
                              void* d_out, int out_size, void* d_ws, size_t ws_size,
                              hipStream_t stream) {
    const float2* xy    = (const float2*)d_in[0];
    const float*  ev    = (const float*)d_in[1];
    const int*    fps   = (const int*)d_in[2];
    const float*  alpha = (const float*)d_in[3];
    const float*  beta  = (const float*)d_in[4];
    float* out = (float*)d_out;

    int*   idx_ws  = (int*)d_ws;                         // 2 MB
    float* mean_ws = (float*)(idx_ws + STOT * NSAMPLE);  // 2 MB
    float* partial = mean_ws + STOT * CH;                // 32 KB
    float* inv_std = partial + STOT;                     // 16 B

    knn_stats_kernel<<<STOT, 256, 0, stream>>>(xy, ev, fps, out,
                                               idx_ws, mean_ws, partial);
    reduce_std_kernel<<<NBATCH, 256, 0, stream>>>(partial, inv_std);
    finalize_kernel<<<STOT, 256, 0, stream>>>(xy, ev, idx_ws, mean_ws, inv_std,
                                              alpha, beta, out);
}